// Round 1
// 941.891 us; speedup vs baseline: 1.2743x; 1.2743x over previous
//
#include <hip/hip_runtime.h>

// RecurrentLinearAttentionPPLM: N=32,H=16,D=64,M=64,T=2048
// Outputs (concatenated in d_out): V [N,H,M], K_cat [N,H,D,T+1], V_cat [N,H,M,T+1]
//
// Streaming-bound op (1.07 GB moved, ~0.27 GFLOP). This version targets
// memory-level parallelism: float4 loads/stores (16 B/lane), explicit
// batch-8 load staging so ~8 KB/wave is in flight per round trip, wave-
// uniform row offsets (SGPR base + VGPR t-offset), and nontemporal stores
// for the write-once outputs so they don't evict inputs from L2/L3.

#define TT   2048
#define TP1  2049
#define DD   64
#define MM   64
#define NHEADS 512
#define EPSF 1e-6f

typedef float f4 __attribute__((ext_vector_type(4)));
// K_cat/V_cat rows have stride 2049 floats -> rows with d%4!=0 are only
// 4-byte aligned. aligned(4) typedef lets the compiler emit (mis)aligned
// dwordx4 stores where legal, or split them -- both correct.
typedef f4 f4u __attribute__((aligned(4)));

__device__ __forceinline__ float feat(float x) {
    // elu(x)+1 : x>0 ? x+1 : exp(x)
    return x > 0.0f ? x + 1.0f : expf(x);
}

__global__ __launch_bounds__(256, 2)
void rla_fused_kernel(const float* __restrict__ query,
                      const float* __restrict__ key,
                      const float* __restrict__ value,
                      const float* __restrict__ k_hist,
                      const float* __restrict__ v_hist,
                      float* __restrict__ out)
{
    const int hh   = blockIdx.x;     // head index 0..511
    const int tid  = threadIdx.x;    // 0..255
    const int lane = tid & 63;
    const int wave = tid >> 6;

    float* outV  = out;                                   // [NH, MM]
    float* outK  = out + (size_t)NHEADS * MM;             // [NH, DD, TP1]
    float* outVc = outK + (size_t)NHEADS * DD * TP1;      // [NH, MM, TP1]

    const float* kh = k_hist + (size_t)hh * DD * TT;
    const float* vh = v_hist + (size_t)hh * MM * TT;
    float* kc = outK  + (size_t)hh * DD * TP1;
    float* vc = outVc + (size_t)hh * MM * TP1;

    __shared__ float Qs[DD];
    __shared__ float Ks[DD];
    __shared__ float Vs[MM];
    __shared__ float wparts[MM * 4];
    __shared__ float sred[4];

    if (tid < DD) {
        Qs[tid] = feat(query[hh * DD + tid]);
        Ks[tid] = feat(key[hh * DD + tid]);
        Vs[tid] = value[hh * MM + tid];
    }
    __syncthreads();

    float acc[MM];
#pragma unroll
    for (int m = 0; m < MM; ++m) acc[m] = 0.0f;
    float ssum = 0.0f;

    // 2 chunks of 1024 time columns; thread owns 4 consecutive columns
    // t..t+3 per chunk (16B-aligned on the load side: row stride 2048).
    for (int chunk = 0; chunk < 2; ++chunk) {
        const int t = chunk * 1024 + 4 * tid;
        const float* khp = kh + t;
        const float* vhp = vh + t;
        float* kcp = kc + t;
        float* vcp = vc + t;

        float s0 = 0.0f, s1 = 0.0f, s2 = 0.0f, s3 = 0.0f;

        // s_t = sum_d Q_d * K[d,t]; copy k_hist -> K_cat.
        // Batch-8 staging: 8 dwordx4 loads (8 KB/wave) in flight before use.
#pragma unroll 1
        for (int d0 = 0; d0 < DD; d0 += 8) {
            f4 kv[8];
#pragma unroll
            for (int j = 0; j < 8; ++j)
                kv[j] = *(const f4*)(khp + (d0 + j) * TT);
#pragma unroll
            for (int j = 0; j < 8; ++j) {
                const float q = Qs[d0 + j];
                s0 += q * kv[j].x;
                s1 += q * kv[j].y;
                s2 += q * kv[j].z;
                s3 += q * kv[j].w;
                __builtin_nontemporal_store(kv[j], (f4u*)(kcp + (d0 + j) * TP1));
            }
        }
        ssum += (s0 + s1) + (s2 + s3);

        // acc[m] += s_t * V[m,t]; copy v_hist -> V_cat
#pragma unroll 1
        for (int m0 = 0; m0 < MM; m0 += 8) {
            f4 vv[8];
#pragma unroll
            for (int j = 0; j < 8; ++j)
                vv[j] = *(const f4*)(vhp + (m0 + j) * TT);
#pragma unroll
            for (int j = 0; j < 8; ++j) {
                acc[m0 + j] += s0 * vv[j].x + s1 * vv[j].y
                             + s2 * vv[j].z + s3 * vv[j].w;
                __builtin_nontemporal_store(vv[j], (f4u*)(vcp + (m0 + j) * TP1));
            }
        }
    }

    // ---- block-reduce ssum (S over history columns) ----
    float r = ssum;
#pragma unroll
    for (int off = 32; off > 0; off >>= 1) r += __shfl_xor(r, off);
    if (lane == 0) sred[wave] = r;
    __syncthreads();
    const float S_hist = sred[0] + sred[1] + sred[2] + sred[3];

    // s for the appended current-step column: Q . feat(K)
    float s_last = 0.0f;
#pragma unroll
    for (int d = 0; d < DD; ++d) s_last += Qs[d] * Ks[d];

    const float Z = 1.0f / (S_hist + s_last + EPSF);

    // ---- reduce acc[m] across 256 threads ----
#pragma unroll
    for (int m = 0; m < MM; ++m) {
        float a = acc[m];
#pragma unroll
        for (int off = 32; off > 0; off >>= 1) a += __shfl_xor(a, off);
        if (lane == 0) wparts[m * 4 + wave] = a;
    }
    __syncthreads();

    if (tid < MM) {
        const float v4 = wparts[tid * 4 + 0] + wparts[tid * 4 + 1] +
                         wparts[tid * 4 + 2] + wparts[tid * 4 + 3];
        // output V (normalized, including current-step column contribution)
        outV[hh * MM + tid] = (v4 + s_last * Vs[tid]) * Z;
        // appended last columns of K_cat / V_cat
        kc[tid * TP1 + TT] = Ks[tid];
        vc[tid * TP1 + TT] = Vs[tid];
    }
}

extern "C" void kernel_launch(void* const* d_in, const int* in_sizes, int n_in,
                              void* d_out, int out_size, void* d_ws, size_t ws_size,
                              hipStream_t stream) {
    const float* query  = (const float*)d_in[0];
    const float* key    = (const float*)d_in[1];
    const float* value  = (const float*)d_in[2];
    const float* k_hist = (const float*)d_in[3];
    const float* v_hist = (const float*)d_in[4];
    float* out = (float*)d_out;

    hipLaunchKernelGGL(rla_fused_kernel, dim3(NHEADS), dim3(256), 0, stream,
                       query, key, value, k_hist, v_hist, out);
}

// Round 2
// 887.070 us; speedup vs baseline: 1.3530x; 1.0618x over previous
//
#include <hip/hip_runtime.h>

// RecurrentLinearAttentionPPLM: N=32,H=16,D=64,M=64,T=2048
// Outputs (concatenated in d_out): V [N,H,M], K_cat [N,H,D,T+1], V_cat [N,H,M,T+1]
//
// Streaming op (537 MB read + 537 MB write). K_cat/V_cat rows have stride
// 2049 floats, so naive f4 stores are misaligned for 3/4 of rows (partial-
// sector HBM writes, +23% WRITE_SIZE in round 1). This version:
//  - loads hist rows as aligned f4, math in registers, stage via LDS
//    (4-row batches, double-buffered 64 KB), read back shifted by
//    (-row mod 4), NT-store fully-aligned f4; <=4 scalar edge stores/row.
//  - intra-granule XOR swizzle in LDS so the shifted 16B-stride reads are
//    2-way (free) instead of 8-way bank conflicts.
//  - no acc[64] array (round 1 spilled it to scratch): V rows are reduced
//    to wave partials immediately per batch via shuffle butterfly.
//  - raw lgkmcnt(0)+s_barrier (NOT __syncthreads) so prefetched global
//    loads for the next batch survive the barrier (no vmcnt(0) drain).

#define TT     2048
#define TP1    2049
#define DD     64
#define MM     64
#define NHEADS 512
#define EPSF   1e-6f
#define NBATCH 16   // 64 rows / 4 rows per batch

typedef float f4 __attribute__((ext_vector_type(4)));

__device__ __forceinline__ float feat(float x) {
    // elu(x)+1 : x>0 ? x+1 : exp(x)
    return x > 0.0f ? x + 1.0f : expf(x);
}

// LDS intra-granule XOR swizzle: logical column `col` of a row lives at
// word (col & ~3) | ((col ^ (col>>2) ^ (col>>5)) & 3).
// (k' = k ^ xr(g), g = col>>2, xr(g) = (g ^ (g>>3)) & 3)
__device__ __forceinline__ int lds_col(int col) {
    return (col & ~3) | ((col ^ (col >> 2) ^ (col >> 5)) & 3);
}

// Workgroup barrier that does NOT drain vmcnt: LDS writes must be visible
// (lgkmcnt(0)), but in-flight global prefetch loads stay outstanding.
__device__ __forceinline__ void barrier_lds() {
    asm volatile("s_waitcnt lgkmcnt(0)\n\ts_barrier" ::: "memory");
}

// Store v's components into a 16B LDS granule with XOR-permuted lanes:
// w[p] = v[p ^ xr]  (xr in 0..3, per-lane -> predicated selects, no branch)
__device__ __forceinline__ void lds_put(float* dst, int xr, f4 v) {
    float a0 = (xr & 1) ? v.y : v.x;
    float a1 = (xr & 1) ? v.x : v.y;
    float a2 = (xr & 1) ? v.w : v.z;
    float a3 = (xr & 1) ? v.z : v.w;
    f4 w;
    w.x = (xr & 2) ? a2 : a0;
    w.y = (xr & 2) ? a3 : a1;
    w.z = (xr & 2) ? a0 : a2;
    w.w = (xr & 2) ? a1 : a3;
    *(f4*)dst = w;
}

__global__ __launch_bounds__(256, 2)
void rla_fused_kernel(const float* __restrict__ query,
                      const float* __restrict__ key,
                      const float* __restrict__ value,
                      const float* __restrict__ k_hist,
                      const float* __restrict__ v_hist,
                      float* __restrict__ out)
{
    const int hh   = blockIdx.x;     // head index 0..511
    const int tid  = threadIdx.x;    // 0..255
    const int lane = tid & 63;
    const int wave = tid >> 6;

    float* outV  = out;                                   // [NH, MM]
    float* outK  = out + (size_t)NHEADS * MM;             // [NH, DD, TP1]
    float* outVc = outK + (size_t)NHEADS * DD * TP1;      // [NH, MM, TP1]

    const float* kh = k_hist + (size_t)hh * DD * TT;
    const float* vh = v_hist + (size_t)hh * MM * TT;
    float* kc = outK  + (size_t)hh * DD * TP1;
    float* vc = outVc + (size_t)hh * MM * TP1;

    __shared__ float Qs[DD];
    __shared__ float Ks[DD];
    __shared__ float Vs[MM];
    __shared__ float buf[2][4][TT];    // 64 KB double-buffered 4-row stage
    __shared__ float vred[4][MM];      // per-wave V partials
    __shared__ float sred[4];

    if (tid < DD) {
        Qs[tid] = feat(query[hh * DD + tid]);
        Ks[tid] = feat(key[hh * DD + tid]);
        Vs[tid] = value[hh * MM + tid];
    }
    __syncthreads();

    const int c0 = 4 * tid;                  // colgroup-0 base column
    const int xr = (tid ^ (tid >> 3)) & 3;   // write-side XOR (same for both granules)

    // s accumulators for this thread's 8 columns:
    // sA[k] ~ col 4*tid+k, sB[k] ~ col 1024+4*tid+k
    float sA[4] = {0.f, 0.f, 0.f, 0.f};
    float sB[4] = {0.f, 0.f, 0.f, 0.f};

// Load one 4-row batch (8 aligned f4 per thread): si -> (r4 = si>>1, g = si&1)
#define LOADT(dst, src, b)                                                   \
    {                                                                        \
        _Pragma("unroll")                                                    \
        for (int si = 0; si < 8; ++si) {                                     \
            const int r4 = si >> 1, g = si & 1;                              \
            dst[si] = *(const f4*)((src) + ((b) * 4 + r4) * TT + g * 1024 + c0); \
        }                                                                    \
    }

// K-phase: FMA into sA/sB, stage into LDS buf[(b)&1]
#define PROCK(regs, b)                                                       \
    {                                                                        \
        float* lb = &buf[(b) & 1][0][0];                                     \
        _Pragma("unroll")                                                    \
        for (int si = 0; si < 8; ++si) {                                     \
            const int r4 = si >> 1, g = si & 1;                              \
            f4 v = regs[si];                                                 \
            const float q = Qs[4 * (b) + r4];                                \
            if (g == 0) {                                                    \
                sA[0] += q * v.x; sA[1] += q * v.y;                          \
                sA[2] += q * v.z; sA[3] += q * v.w;                          \
            } else {                                                         \
                sB[0] += q * v.x; sB[1] += q * v.y;                          \
                sB[2] += q * v.z; sB[3] += q * v.w;                          \
            }                                                                \
            lds_put(lb + r4 * TT + g * 1024 + c0, xr, v);                    \
        }                                                                    \
    }

// V-phase: dot with sA/sB, immediate wave-reduce (no acc[64] array!)
#define PROCV(regs, b)                                                       \
    {                                                                        \
        float* lb = &buf[(b) & 1][0][0];                                     \
        float p0 = 0.f, p1 = 0.f, p2 = 0.f, p3 = 0.f;                        \
        _Pragma("unroll")                                                    \
        for (int si = 0; si < 8; ++si) {                                     \
            const int r4 = si >> 1, g = si & 1;                              \
            f4 v = regs[si];                                                 \
            float d;                                                         \
            if (g == 0) d = sA[0]*v.x + sA[1]*v.y + sA[2]*v.z + sA[3]*v.w;   \
            else        d = sB[0]*v.x + sB[1]*v.y + sB[2]*v.z + sB[3]*v.w;   \
            if      (r4 == 0) p0 += d;                                       \
            else if (r4 == 1) p1 += d;                                       \
            else if (r4 == 2) p2 += d;                                       \
            else              p3 += d;                                       \
            lds_put(lb + r4 * TT + g * 1024 + c0, xr, v);                    \
        }                                                                    \
        _Pragma("unroll")                                                    \
        for (int off = 32; off; off >>= 1) {                                 \
            p0 += __shfl_xor(p0, off); p1 += __shfl_xor(p1, off);            \
            p2 += __shfl_xor(p2, off); p3 += __shfl_xor(p3, off);            \
        }                                                                    \
        if (lane == 0) {                                                     \
            vred[wave][4 * (b) + 0] = p0; vred[wave][4 * (b) + 1] = p1;      \
            vred[wave][4 * (b) + 2] = p2; vred[wave][4 * (b) + 3] = p3;      \
        }                                                                    \
    }

// Aligned store of one batch from LDS to global (shift = (-row) mod 4).
// shift depends only on r4 (rows are 4b+r4): r4: 0->0, 1->3, 2->2, 3->1.
#define STORE_PHASE(b, dstbase)                                              \
    {                                                                        \
        const float* lb = &buf[(b) & 1][0][0];                               \
        _Pragma("unroll")                                                    \
        for (int si = 0; si < 8; ++si) {                                     \
            const int r4 = si >> 1, g = si & 1;                              \
            const int shift = (4 - r4) & 3;                                  \
            const int sidx = g * 256 + tid;                                  \
            if (shift == 0 || sidx < 511) {                                  \
                const int t0 = shift + 4 * sidx;                             \
                const float* rp = lb + r4 * TT;                              \
                f4 w;                                                        \
                w.x = rp[lds_col(t0 + 0)];                                   \
                w.y = rp[lds_col(t0 + 1)];                                   \
                w.z = rp[lds_col(t0 + 2)];                                   \
                w.w = rp[lds_col(t0 + 3)];                                   \
                __builtin_nontemporal_store(w,                               \
                    (f4*)((dstbase) + (size_t)(4 * (b) + r4) * TP1 + t0));   \
            }                                                                \
        }                                                                    \
        if (tid < 4) {                                                       \
            const int r4 = tid;                                              \
            const int shift = (4 - r4) & 3;                                  \
            const float* rp = lb + r4 * TT;                                  \
            const int r = 4 * (b) + r4;                                      \
            if (shift != 0) {                                                \
                _Pragma("unroll")                                            \
                for (int j = 0; j < 4; ++j) {                                \
                    const int col = (j < shift) ? j : (2044 + j);            \
                    __builtin_nontemporal_store(rp[lds_col(col)],            \
                        (dstbase) + (size_t)r * TP1 + col);                  \
                }                                                            \
            }                                                                \
        }                                                                    \
    }

    f4 ra[8], rb[8];

    // ---------------- K phase ----------------
    LOADT(ra, kh, 0);
    for (int b = 0; b < NBATCH; b += 2) {
        if (b + 1 < NBATCH) LOADT(rb, kh, b + 1);
        PROCK(ra, b);
        barrier_lds();
        STORE_PHASE(b, kc);
        if (b + 2 < NBATCH) LOADT(ra, kh, b + 2);
        PROCK(rb, b + 1);
        barrier_lds();
        STORE_PHASE(b + 1, kc);
    }

    // ---------------- V phase ----------------
    LOADT(ra, vh, 0);
    for (int b = 0; b < NBATCH; b += 2) {
        if (b + 1 < NBATCH) LOADT(rb, vh, b + 1);
        PROCV(ra, b);
        barrier_lds();
        STORE_PHASE(b, vc);
        if (b + 2 < NBATCH) LOADT(ra, vh, b + 2);
        PROCV(rb, b + 1);
        barrier_lds();
        STORE_PHASE(b + 1, vc);
    }

    // ---------------- epilogue ----------------
    float ssum = sA[0] + sA[1] + sA[2] + sA[3] + sB[0] + sB[1] + sB[2] + sB[3];
    float rsum = ssum;
#pragma unroll
    for (int off = 32; off; off >>= 1) rsum += __shfl_xor(rsum, off);
    if (lane == 0) sred[wave] = rsum;
    __syncthreads();

    const float S_hist = sred[0] + sred[1] + sred[2] + sred[3];
    float s_last = 0.f;
#pragma unroll
    for (int d = 0; d < DD; ++d) s_last += Qs[d] * Ks[d];
    const float Z = 1.0f / (S_hist + s_last + EPSF);

    if (tid < MM) {
        const float v4 = vred[0][tid] + vred[1][tid] + vred[2][tid] + vred[3][tid];
        outV[hh * MM + tid] = (v4 + s_last * Vs[tid]) * Z;
        // appended last columns of K_cat / V_cat
        kc[tid * TP1 + TT] = Ks[tid];
        vc[tid * TP1 + TT] = Vs[tid];
    }

#undef LOADT
#undef PROCK
#undef PROCV
#undef STORE_PHASE
}

extern "C" void kernel_launch(void* const* d_in, const int* in_sizes, int n_in,
                              void* d_out, int out_size, void* d_ws, size_t ws_size,
                              hipStream_t stream) {
    const float* query  = (const float*)d_in[0];
    const float* key    = (const float*)d_in[1];
    const float* value  = (const float*)d_in[2];
    const float* k_hist = (const float*)d_in[3];
    const float* v_hist = (const float*)d_in[4];
    float* out = (float*)d_out;

    hipLaunchKernelGGL(rla_fused_kernel, dim3(NHEADS), dim3(256), 0, stream,
                       query, key, value, k_hist, v_hist, out);
}